// Round 3
// baseline (328.838 us; speedup 1.0000x reference)
//
#include <hip/hip_runtime.h>
#include <math.h>

#define H 2048

__device__ __forceinline__ float sigmoidf_(float v) {
    return 1.0f / (1.0f + expf(-v));
}

__device__ __forceinline__ float dot4(float4 a, float4 b) {
    return a.x * b.x + a.y * b.y + a.z * b.z + a.w * b.w;
}

// 4 interleaved butterfly chains, depth 6.
__device__ __forceinline__ void bfly4(float& a, float& b, float& c, float& d) {
#pragma unroll
    for (int off = 32; off > 0; off >>= 1) {
        a += __shfl_down(a, off, 64);
        b += __shfl_down(b, off, 64);
        c += __shfl_down(c, off, 64);
        d += __shfl_down(d, off, 64);
    }
}

// 8 K-chunk float4 loads (one element, one gate pair) held as named regs.
struct W8 { float4 a0, a1, b0, b1, c0, c1, d0, d1; };

// Layers 1/2: rows {row0, row0+H} of both Wih and Whh.
__device__ __forceinline__ void gp_load(const float* __restrict__ Wih,
                                        const float* __restrict__ Whh,
                                        int row0, int idx, W8& r) {
    const float4* wi0 = (const float4*)(Wih + (size_t)row0 * H);
    const float4* wi1 = (const float4*)(Wih + (size_t)(row0 + H) * H);
    const float4* wh0 = (const float4*)(Whh + (size_t)row0 * H);
    const float4* wh1 = (const float4*)(Whh + (size_t)(row0 + H) * H);
    r.a0 = wi0[idx]; r.a1 = wi0[idx + 64];
    r.b0 = wh0[idx]; r.b1 = wh0[idx + 64];
    r.c0 = wi1[idx]; r.c1 = wi1[idx + 64];
    r.d0 = wh1[idx]; r.d1 = wh1[idx + 64];
}

__device__ __forceinline__ void gp_consume(const W8& r,
                                           float4 xv0, float4 xv1,
                                           float4 hv0, float4 hv1,
                                           float& sA, float& sB) {
    sA = (dot4(r.a0, xv0) + dot4(r.b0, hv0)) + (dot4(r.a1, xv1) + dot4(r.b1, hv1));
    sB = (dot4(r.c0, xv0) + dot4(r.d0, hv0)) + (dot4(r.c1, xv1) + dot4(r.d1, hv1));
}

// Layer 0: the 4 Whh gate rows of one element.
__device__ __forceinline__ void l0_load(const float* __restrict__ Whh,
                                        int t, int idx, W8& r) {
    const float4* wi = (const float4*)(Whh + (size_t)t * H);
    const float4* wf = (const float4*)(Whh + (size_t)(H + t) * H);
    const float4* wg = (const float4*)(Whh + (size_t)(2 * H + t) * H);
    const float4* wo = (const float4*)(Whh + (size_t)(3 * H + t) * H);
    r.a0 = wi[idx]; r.a1 = wi[idx + 64];
    r.b0 = wf[idx]; r.b1 = wf[idx + 64];
    r.c0 = wg[idx]; r.c1 = wg[idx + 64];
    r.d0 = wo[idx]; r.d1 = wo[idx + 64];
}

__device__ __forceinline__ void l0_consume(const W8& r, float4 hv0, float4 hv1,
                                           float& si, float& sf, float& sg, float& so) {
    si = dot4(r.a0, hv0) + dot4(r.a1, hv1);
    sf = dot4(r.b0, hv0) + dot4(r.b1, hv1);
    sg = dot4(r.c0, hv0) + dot4(r.c1, hv1);
    so = dot4(r.d0, hv0) + dot4(r.d1, hv1);
}

// Final gate math for one element; b* are bih+bhh (+x*Wih0 for layer 0)
// pre-combined in SGPRs.
__device__ __forceinline__ void lstm_tail(const float (*part)[4][4], int e, int t,
                                          float bi, float bf, float bg, float bo,
                                          float cprev,
                                          float* __restrict__ hout,
                                          float* __restrict__ cout) {
    float gi = part[e][0][0] + part[e][1][0] + part[e][2][0] + part[e][3][0] + bi;
    float gf = part[e][0][1] + part[e][1][1] + part[e][2][1] + part[e][3][1] + bf;
    float gg = part[e][0][2] + part[e][1][2] + part[e][2][2] + part[e][3][2] + bg;
    float go = part[e][0][3] + part[e][1][3] + part[e][2][3] + part[e][3][3] + bo;
    float c2 = sigmoidf_(gf) * cprev + sigmoidf_(gi) * tanhf(gg);
    float h2 = sigmoidf_(go) * tanhf(c2);
    cout[t] = c2;
    hout[t] = h2;
}

// Layers 1,2 — split-K (4 waves = K-quarters) x 2 elements per block,
// register-double-buffered: element t1's 16 weight loads are issued before
// t0's butterfly, so the ~700cy DS-reduce phase runs with 16KB/wave of global
// loads still in flight (counted-vmcnt pattern; single __syncthreads at end).
__global__ __launch_bounds__(256, 4)
void lstm_layer(const float* __restrict__ Wih, const float* __restrict__ Whh,
                const float* __restrict__ bih, const float* __restrict__ bhh,
                const float* __restrict__ xin,  // [H] prev-layer h
                const float* __restrict__ hin,  // [H]
                const float* __restrict__ cin,  // [H]
                float* __restrict__ hout, float* __restrict__ cout)
{
    const int t0   = blockIdx.x * 2;
    const int t1   = t0 + 1;
    const int tid  = threadIdx.x;
    const int w    = tid >> 6;
    const int lane = tid & 63;
    const int idx  = (w << 7) + lane;   // float4 index; row = 512 float4

    // uniform scalar loads -> SGPRs; biases pre-combined
    const float b_i0 = bih[t0]         + bhh[t0];
    const float b_f0 = bih[H + t0]     + bhh[H + t0];
    const float b_g0 = bih[2 * H + t0] + bhh[2 * H + t0];
    const float b_o0 = bih[3 * H + t0] + bhh[3 * H + t0];
    const float b_i1 = bih[t1]         + bhh[t1];
    const float b_f1 = bih[H + t1]     + bhh[H + t1];
    const float b_g1 = bih[2 * H + t1] + bhh[2 * H + t1];
    const float b_o1 = bih[3 * H + t1] + bhh[3 * H + t1];
    const float cp0 = cin[t0], cp1 = cin[t1];

    const float4* x4 = (const float4*)xin;
    const float4* h4 = (const float4*)hin;
    const float4 xv0 = x4[idx], xv1 = x4[idx + 64];
    const float4 hv0 = h4[idx], hv1 = h4[idx + 64];

    W8 r00, r01, r10, r11;               // r[elem][gate-pair]
    gp_load(Wih, Whh, t0,         idx, r00);
    gp_load(Wih, Whh, 2 * H + t0, idx, r01);
    gp_load(Wih, Whh, t1,         idx, r10);   // e1 half A in flight

    float ei, ef, eg, eo;
    gp_consume(r00, xv0, xv1, hv0, hv1, ei, ef);   // frees r00 regs
    gp_load(Wih, Whh, 2 * H + t1, idx, r11);       // e1 half B in flight
    gp_consume(r01, xv0, xv1, hv0, hv1, eg, eo);

    bfly4(ei, ef, eg, eo);               // e1's 16 loads outstanding here

    __shared__ float part[2][4][4];
    if (lane == 0) {
        part[0][w][0] = ei; part[0][w][1] = ef;
        part[0][w][2] = eg; part[0][w][3] = eo;
    }

    float fi, ff, fg, fo;
    gp_consume(r10, xv0, xv1, hv0, hv1, fi, ff);
    gp_consume(r11, xv0, xv1, hv0, hv1, fg, fo);
    bfly4(fi, ff, fg, fo);
    if (lane == 0) {
        part[1][w][0] = fi; part[1][w][1] = ff;
        part[1][w][2] = fg; part[1][w][3] = fo;
    }

    __syncthreads();   // single full drain per block; all loads consumed by now
    if (lane == 0 && w == 0)
        lstm_tail(part, 0, t0, b_i0, b_f0, b_g0, b_o0, cp0, hout, cout);
    if (lane == 0 && w == 1)
        lstm_tail(part, 1, t1, b_i1, b_f1, b_g1, b_o1, cp1, hout, cout);
}

// Layer 0 — Wih0 is [4H,1]; x*Wih0 folded into the combined bias. Both
// elements' 16 Whh loads (64 VGPRs) are issued up front; butterfly e0 runs
// with e1's loads in flight.
__global__ __launch_bounds__(256, 4)
void lstm_layer0(const float* __restrict__ Wih0,  // [4H]
                 const float* __restrict__ Whh,   // [4H,H]
                 const float* __restrict__ bih, const float* __restrict__ bhh,
                 const float* __restrict__ xs,    // [1]
                 const float* __restrict__ hin, const float* __restrict__ cin,
                 float* __restrict__ hout, float* __restrict__ cout)
{
    const int t0   = blockIdx.x * 2;
    const int t1   = t0 + 1;
    const int tid  = threadIdx.x;
    const int w    = tid >> 6;
    const int lane = tid & 63;
    const int idx  = (w << 7) + lane;

    const float x = xs[0];
    const float b_i0 = bih[t0]         + bhh[t0]         + x * Wih0[t0];
    const float b_f0 = bih[H + t0]     + bhh[H + t0]     + x * Wih0[H + t0];
    const float b_g0 = bih[2 * H + t0] + bhh[2 * H + t0] + x * Wih0[2 * H + t0];
    const float b_o0 = bih[3 * H + t0] + bhh[3 * H + t0] + x * Wih0[3 * H + t0];
    const float b_i1 = bih[t1]         + bhh[t1]         + x * Wih0[t1];
    const float b_f1 = bih[H + t1]     + bhh[H + t1]     + x * Wih0[H + t1];
    const float b_g1 = bih[2 * H + t1] + bhh[2 * H + t1] + x * Wih0[2 * H + t1];
    const float b_o1 = bih[3 * H + t1] + bhh[3 * H + t1] + x * Wih0[3 * H + t1];
    const float cp0 = cin[t0], cp1 = cin[t1];

    const float4* h4 = (const float4*)hin;
    const float4 hv0 = h4[idx], hv1 = h4[idx + 64];

    W8 r0, r1;
    l0_load(Whh, t0, idx, r0);
    l0_load(Whh, t1, idx, r1);           // both elements in flight (64 regs)

    float ei, ef, eg, eo;
    l0_consume(r0, hv0, hv1, ei, ef, eg, eo);
    bfly4(ei, ef, eg, eo);               // e1's 8 loads outstanding here

    __shared__ float part[2][4][4];
    if (lane == 0) {
        part[0][w][0] = ei; part[0][w][1] = ef;
        part[0][w][2] = eg; part[0][w][3] = eo;
    }

    float fi, ff, fg, fo;
    l0_consume(r1, hv0, hv1, fi, ff, fg, fo);
    bfly4(fi, ff, fg, fo);
    if (lane == 0) {
        part[1][w][0] = fi; part[1][w][1] = ff;
        part[1][w][2] = fg; part[1][w][3] = fo;
    }

    __syncthreads();
    if (lane == 0 && w == 0)
        lstm_tail(part, 0, t0, b_i0, b_f0, b_g0, b_o0, cp0, hout, cout);
    if (lane == 0 && w == 1)
        lstm_tail(part, 1, t1, b_i1, b_f1, b_g1, b_o1, cp1, hout, cout);
}

// y = dot(Wout, h) + bout   (single block)
__global__ __launch_bounds__(256)
void out_proj(const float* __restrict__ Wout,
              const float* __restrict__ bout,
              const float* __restrict__ h,
              float* __restrict__ y)
{
    __shared__ float partl[4];
    const int tid = threadIdx.x;
    const float4* W4 = (const float4*)Wout;
    const float4* h4 = (const float4*)h;
    float acc = 0.0f;
#pragma unroll
    for (int k = 0; k < 2; ++k) {
        int i = tid + 256 * k;
        float4 a = W4[i];
        float4 b = h4[i];
        acc += a.x * b.x + a.y * b.y + a.z * b.z + a.w * b.w;
    }
#pragma unroll
    for (int off = 32; off > 0; off >>= 1) acc += __shfl_down(acc, off, 64);
    if ((tid & 63) == 0) partl[tid >> 6] = acc;
    __syncthreads();
    if (tid == 0) y[0] = partl[0] + partl[1] + partl[2] + partl[3] + bout[0];
}

extern "C" void kernel_launch(void* const* d_in, const int* in_sizes, int n_in,
                              void* d_out, int out_size, void* d_ws, size_t ws_size,
                              hipStream_t stream) {
    const float* x    = (const float*)d_in[0];
    const float* hin  = (const float*)d_in[1];   // [3,1,H]
    const float* cin  = (const float*)d_in[2];   // [3,1,H]
    const float* Wih0 = (const float*)d_in[3];
    const float* Whh0 = (const float*)d_in[4];
    const float* bih0 = (const float*)d_in[5];
    const float* bhh0 = (const float*)d_in[6];
    const float* Wih1 = (const float*)d_in[7];
    const float* Whh1 = (const float*)d_in[8];
    const float* bih1 = (const float*)d_in[9];
    const float* bhh1 = (const float*)d_in[10];
    const float* Wih2 = (const float*)d_in[11];
    const float* Whh2 = (const float*)d_in[12];
    const float* bih2 = (const float*)d_in[13];
    const float* bhh2 = (const float*)d_in[14];
    const float* Wout = (const float*)d_in[15];
    const float* bout = (const float*)d_in[16];

    float* out = (float*)d_out;
    float* y  = out;              // [1]
    float* hN = out + 1;          // [3,H]
    float* cN = out + 1 + 3 * H;  // [3,H]

    lstm_layer0<<<1024, 256, 0, stream>>>(Wih0, Whh0, bih0, bhh0, x,
                                          hin, cin, hN, cN);
    lstm_layer<<<1024, 256, 0, stream>>>(Wih1, Whh1, bih1, bhh1,
                                         hN, hin + H, cin + H,
                                         hN + H, cN + H);
    lstm_layer<<<1024, 256, 0, stream>>>(Wih2, Whh2, bih2, bhh2,
                                         hN + H, hin + 2 * H, cin + 2 * H,
                                         hN + 2 * H, cN + 2 * H);
    out_proj<<<1, 256, 0, stream>>>(Wout, bout, hN + 2 * H, y);
}